// Round 1
// baseline (9222.285 us; speedup 1.0000x reference)
//
#include <hip/hip_runtime.h>
#include <hip/hip_bf16.h>

// Shapes: H=8, D=128, DH=16, B=32, N=512
constexpr int H_ = 8;
constexpr int D_ = 128;
constexpr int DH_ = 16;
constexpr int B_ = 32;
constexpr int N_ = 512;
constexpr int NT_ = 4;   // query rows per attn block

// ---------------------------------------------------------------------------
// Kernel 1: QKV projection.  Q/K/V layout: [H][B][N][DH]
// block = (b, 32-row n tile), 256 threads
// ---------------------------------------------------------------------------
__global__ __launch_bounds__(256) void qkv_kernel(
    const float* __restrict__ h_fea, const float* __restrict__ Wq,
    const float* __restrict__ Wk, const float* __restrict__ Wv,
    float* __restrict__ Q, float* __restrict__ K, float* __restrict__ V)
{
  __shared__ float hs[32][129];                 // padded: n-rows spread banks
  __shared__ float wqs[128][17], wks[128][17], wvs[128][17];
  const int t = threadIdx.x;
  const int b = blockIdx.x >> 4;
  const int n0 = (blockIdx.x & 15) << 5;

  // load h_fea tile (32x128), coalesced float4
#pragma unroll
  for (int i = 0; i < 4; ++i) {
    int idx4 = t + i * 256;
    int nl = idx4 >> 5, c = (idx4 & 31) * 4;
    float4 v = ((const float4*)(h_fea + ((size_t)(b * N_ + n0 + nl)) * D_))[idx4 & 31];
    hs[nl][c] = v.x; hs[nl][c + 1] = v.y; hs[nl][c + 2] = v.z; hs[nl][c + 3] = v.w;
  }

  const int nl = t >> 3;
  const int e0 = (t & 7) * 2;
  for (int h = 0; h < H_; ++h) {
    __syncthreads();   // protect W LDS from previous iteration's readers
#pragma unroll
    for (int i = 0; i < 8; ++i) {
      int idx = t + i * 256;           // 2048 weights per matrix per head
      int d = idx >> 4, e = idx & 15;
      wqs[d][e] = Wq[h * 2048 + idx];
      wks[d][e] = Wk[h * 2048 + idx];
      wvs[d][e] = Wv[h * 2048 + idx];
    }
    __syncthreads();
    float q0 = 0.f, q1 = 0.f, k0 = 0.f, k1 = 0.f, v0 = 0.f, v1 = 0.f;
    for (int d = 0; d < D_; ++d) {
      float x = hs[nl][d];
      q0 = fmaf(x, wqs[d][e0], q0); q1 = fmaf(x, wqs[d][e0 + 1], q1);
      k0 = fmaf(x, wks[d][e0], k0); k1 = fmaf(x, wks[d][e0 + 1], k1);
      v0 = fmaf(x, wvs[d][e0], v0); v1 = fmaf(x, wvs[d][e0 + 1], v1);
    }
    size_t o = ((size_t)(h * B_ + b) * N_ + n0 + nl) * DH_ + e0;
    Q[o] = q0; Q[o + 1] = q1;
    K[o] = k0; K[o + 1] = k1;
    V[o] = v0; V[o + 1] = v1;
  }
}

// ---------------------------------------------------------------------------
// Kernel 2: fused qk + aux passthrough + score MLP + softmax + PV
// block = (b, NT_ query rows), 256 threads (4 waves)
// ---------------------------------------------------------------------------
__global__ __launch_bounds__(256) void attn_kernel(
    const float* __restrict__ Q, const float* __restrict__ K, const float* __restrict__ V,
    const float* __restrict__ aux, const float* __restrict__ W1, const float* __restrict__ b1,
    const float* __restrict__ W2, const float* __restrict__ b2,
    float* __restrict__ heads, float* __restrict__ out_aux)
{
  __shared__ float Qs[NT_][H_][DH_];
  __shared__ float W1s[16][16];
  __shared__ float W2s[16][8];
  __shared__ float b1s[16];
  __shared__ float b2s[8];
  __shared__ float sc[NT_][N_][9];      // stride 9 floats: bank-spread
  __shared__ float invl[NT_][H_];
  __shared__ float heads_s[NT_][H_ * DH_];

  const int t = threadIdx.x;
  const int b = blockIdx.x >> 7;              // N_/NT_ = 128 tiles per b
  const int n0 = (blockIdx.x & 127) * NT_;

  // stage MLP weights + Q rows
  W1s[t >> 4][t & 15] = W1[t];
  if (t < 128) W2s[t >> 3][t & 7] = W2[t];
  if (t < 16) b1s[t] = b1[t];
  if (t >= 16 && t < 24) b2s[t - 16] = b2[t - 16];
#pragma unroll
  for (int i = 0; i < 2; ++i) {
    int idx = t + i * 256;                    // NT_*H_*DH_ = 512
    int nl = idx >> 7, h = (idx >> 4) & 7, e = idx & 15;
    Qs[nl][h][e] = Q[((size_t)(h * B_ + b) * N_ + n0 + nl) * DH_ + e];
  }
  __syncthreads();

  // ---- Phase A: scores for all m ----
#pragma unroll
  for (int iter = 0; iter < N_ / 256; ++iter) {
    const int m = t + iter * 256;
    float qk[NT_][H_];
#pragma unroll
    for (int h = 0; h < H_; ++h) {
      const float4* kp = (const float4*)(K + ((size_t)(h * B_ + b) * N_ + m) * DH_);
      float4 k0 = kp[0], k1 = kp[1], k2 = kp[2], k3 = kp[3];
#pragma unroll
      for (int nl = 0; nl < NT_; ++nl) {
        const float* q = Qs[nl][h];
        qk[nl][h] =
            q[0] * k0.x + q[1] * k0.y + q[2] * k0.z + q[3] * k0.w
          + q[4] * k1.x + q[5] * k1.y + q[6] * k1.z + q[7] * k1.w
          + q[8] * k2.x + q[9] * k2.y + q[10] * k2.z + q[11] * k2.w
          + q[12] * k3.x + q[13] * k3.y + q[14] * k3.z + q[15] * k3.w;
      }
    }
#pragma unroll
    for (int nl = 0; nl < NT_; ++nl) {
      float c[16];
#pragma unroll
      for (int h = 0; h < H_; ++h) c[h] = qk[nl][h];
#pragma unroll
      for (int h = 0; h < H_; ++h) {
        size_t ai = ((size_t)(h * B_ + b) * N_ + n0 + nl) * N_ + m;
        float av = aux[ai];
        out_aux[ai] = av;                     // fused passthrough copy
        c[8 + h] = av;
      }
      float hid[16];
#pragma unroll
      for (int j = 0; j < 16; ++j) hid[j] = b1s[j];
#pragma unroll
      for (int i = 0; i < 16; ++i) {
        float ci = c[i];
#pragma unroll
        for (int j = 0; j < 16; ++j) hid[j] = fmaf(ci, W1s[i][j], hid[j]);
      }
      float s8[8];
#pragma unroll
      for (int h = 0; h < 8; ++h) s8[h] = b2s[h];
#pragma unroll
      for (int j = 0; j < 16; ++j) {
        float hj = fmaxf(hid[j], 0.f);
#pragma unroll
        for (int h = 0; h < 8; ++h) s8[h] = fmaf(hj, W2s[j][h], s8[h]);
      }
#pragma unroll
      for (int h = 0; h < 8; ++h) sc[nl][m][h] = s8[h];
    }
  }
  __syncthreads();

  // ---- Phase B: softmax over m per (nl,h); 8 threads per pair ----
  {
    const int p = t >> 3, g = t & 7;
    const int nl = p >> 3, h = p & 7;
    float mx = -1e30f;
    for (int j = 0; j < 64; ++j) mx = fmaxf(mx, sc[nl][g + 8 * j][h]);
#pragma unroll
    for (int o = 4; o; o >>= 1) mx = fmaxf(mx, __shfl_xor(mx, o, 8));
    float sum = 0.f;
    for (int j = 0; j < 64; ++j) {
      int m = g + 8 * j;
      float e = __expf(sc[nl][m][h] - mx);
      sc[nl][m][h] = e;
      sum += e;
    }
#pragma unroll
    for (int o = 4; o; o >>= 1) sum += __shfl_xor(sum, o, 8);
    if (g == 0) invl[nl][h] = 1.0f / sum;
  }
  __syncthreads();

  // ---- Phase C: PV.  wave w handles heads 2w, 2w+1 ----
  {
    const int wv = t >> 6, lane = t & 63;
    const int h0 = wv * 2, h1 = h0 + 1;
    const float* V0 = V + (size_t)(h0 * B_ + b) * N_ * DH_;
    const float* V1 = V + (size_t)(h1 * B_ + b) * N_ * DH_;
#pragma unroll
    for (int nl = 0; nl < NT_; ++nl) {
      float a0acc[16], a1acc[16];
#pragma unroll
      for (int i = 0; i < 16; ++i) { a0acc[i] = 0.f; a1acc[i] = 0.f; }
#pragma unroll
      for (int k = 0; k < 8; ++k) {
        int m = lane + 64 * k;
        float a0 = sc[nl][m][h0];
        float a1 = sc[nl][m][h1];
        const float4* vp0 = (const float4*)(V0 + m * DH_);
        const float4* vp1 = (const float4*)(V1 + m * DH_);
        float4 u;
        u = vp0[0]; a0acc[0] = fmaf(a0,u.x,a0acc[0]); a0acc[1] = fmaf(a0,u.y,a0acc[1]); a0acc[2] = fmaf(a0,u.z,a0acc[2]); a0acc[3] = fmaf(a0,u.w,a0acc[3]);
        u = vp0[1]; a0acc[4] = fmaf(a0,u.x,a0acc[4]); a0acc[5] = fmaf(a0,u.y,a0acc[5]); a0acc[6] = fmaf(a0,u.z,a0acc[6]); a0acc[7] = fmaf(a0,u.w,a0acc[7]);
        u = vp0[2]; a0acc[8] = fmaf(a0,u.x,a0acc[8]); a0acc[9] = fmaf(a0,u.y,a0acc[9]); a0acc[10]= fmaf(a0,u.z,a0acc[10]); a0acc[11]= fmaf(a0,u.w,a0acc[11]);
        u = vp0[3]; a0acc[12]= fmaf(a0,u.x,a0acc[12]); a0acc[13]= fmaf(a0,u.y,a0acc[13]); a0acc[14]= fmaf(a0,u.z,a0acc[14]); a0acc[15]= fmaf(a0,u.w,a0acc[15]);
        u = vp1[0]; a1acc[0] = fmaf(a1,u.x,a1acc[0]); a1acc[1] = fmaf(a1,u.y,a1acc[1]); a1acc[2] = fmaf(a1,u.z,a1acc[2]); a1acc[3] = fmaf(a1,u.w,a1acc[3]);
        u = vp1[1]; a1acc[4] = fmaf(a1,u.x,a1acc[4]); a1acc[5] = fmaf(a1,u.y,a1acc[5]); a1acc[6] = fmaf(a1,u.z,a1acc[6]); a1acc[7] = fmaf(a1,u.w,a1acc[7]);
        u = vp1[2]; a1acc[8] = fmaf(a1,u.x,a1acc[8]); a1acc[9] = fmaf(a1,u.y,a1acc[9]); a1acc[10]= fmaf(a1,u.z,a1acc[10]); a1acc[11]= fmaf(a1,u.w,a1acc[11]);
        u = vp1[3]; a1acc[12]= fmaf(a1,u.x,a1acc[12]); a1acc[13]= fmaf(a1,u.y,a1acc[13]); a1acc[14]= fmaf(a1,u.z,a1acc[14]); a1acc[15]= fmaf(a1,u.w,a1acc[15]);
      }
#pragma unroll
      for (int o = 32; o; o >>= 1) {
#pragma unroll
        for (int i = 0; i < 16; ++i) {
          a0acc[i] += __shfl_down(a0acc[i], o);
          a1acc[i] += __shfl_down(a1acc[i], o);
        }
      }
      if (lane == 0) {
        float i0 = invl[nl][h0], i1 = invl[nl][h1];
#pragma unroll
        for (int i = 0; i < 16; ++i) {
          heads_s[nl][h0 * 16 + i] = a0acc[i] * i0;
          heads_s[nl][h1 * 16 + i] = a1acc[i] * i1;
        }
      }
    }
  }
  __syncthreads();
#pragma unroll
  for (int i = 0; i < 2; ++i) {
    int idx = t + i * 256;
    int nl = idx >> 7, d = idx & 127;
    heads[((size_t)(b * N_ + n0 + nl)) * D_ + d] = heads_s[nl][d];
  }
}

// ---------------------------------------------------------------------------
// Kernel 3: X = heads @ W_out + h_fea.  16 rows per block, 256 threads.
// ---------------------------------------------------------------------------
__global__ __launch_bounds__(256) void wout_kernel(
    const float* __restrict__ heads, const float* __restrict__ Wo,
    const float* __restrict__ h_fea, float* __restrict__ X)
{
  __shared__ float wos[128][128];
  __shared__ float hsd[16][129];
  const int t = threadIdx.x;
  const int r0 = blockIdx.x * 16;
#pragma unroll
  for (int i = 0; i < 16; ++i) {
    int idx4 = t + i * 256;                   // 4096 float4 = full 128x128
    float4 v = ((const float4*)Wo)[idx4];
    int k = idx4 >> 5, c = (idx4 & 31) * 4;
    wos[k][c] = v.x; wos[k][c + 1] = v.y; wos[k][c + 2] = v.z; wos[k][c + 3] = v.w;
  }
#pragma unroll
  for (int i = 0; i < 2; ++i) {
    int idx4 = t + i * 256;                   // 512 float4 = 16x128
    int r = idx4 >> 5, c = (idx4 & 31) * 4;
    float4 v = ((const float4*)(heads + (size_t)(r0 + r) * D_))[idx4 & 31];
    hsd[r][c] = v.x; hsd[r][c + 1] = v.y; hsd[r][c + 2] = v.z; hsd[r][c + 3] = v.w;
  }
  __syncthreads();
  const int r = t >> 4, dg = t & 15;
  float acc[8];
#pragma unroll
  for (int i = 0; i < 8; ++i) acc[i] = 0.f;
  for (int k = 0; k < 128; ++k) {
    float hv = hsd[r][k];
#pragma unroll
    for (int i = 0; i < 8; ++i) acc[i] = fmaf(hv, wos[k][dg + 16 * i], acc[i]);
  }
  size_t base = (size_t)(r0 + r) * D_;
#pragma unroll
  for (int i = 0; i < 8; ++i) {
    int d = dg + 16 * i;
    X[base + d] = acc[i] + h_fea[base + d];
  }
}

// ---------------------------------------------------------------------------
// Kernel 4: per-batch layernorm over (N,D), unbiased var (ddof=1)
// ---------------------------------------------------------------------------
__global__ __launch_bounds__(1024) void ln_kernel(
    const float* __restrict__ X, float* __restrict__ out)
{
  const int b = blockIdx.x;
  const int t = threadIdx.x;
  const float4* xp = (const float4*)(X + (size_t)b * (N_ * D_));
  float s = 0.f, sq = 0.f;
  for (int i = t; i < (N_ * D_) / 4; i += 1024) {
    float4 v = xp[i];
    s += v.x + v.y + v.z + v.w;
    sq += v.x * v.x + v.y * v.y + v.z * v.z + v.w * v.w;
  }
  __shared__ float rs[16], rq[16];
  __shared__ float mean_s, rstd_s;
#pragma unroll
  for (int o = 32; o; o >>= 1) { s += __shfl_down(s, o); sq += __shfl_down(sq, o); }
  const int w = t >> 6, lane = t & 63;
  if (lane == 0) { rs[w] = s; rq[w] = sq; }
  __syncthreads();
  if (t == 0) {
    float ts = 0.f, tq = 0.f;
    for (int i = 0; i < 16; ++i) { ts += rs[i]; tq += rq[i]; }
    const float M = (float)(N_ * D_);
    float mean = ts / M;
    float var = (tq - ts * ts / M) / (M - 1.0f);
    mean_s = mean;
    rstd_s = rsqrtf(var + 1e-5f);
  }
  __syncthreads();
  const float mean = mean_s, rstd = rstd_s;
  float4* op = (float4*)(out + (size_t)b * (N_ * D_));
  for (int i = t; i < (N_ * D_) / 4; i += 1024) {
    float4 v = xp[i];
    v.x = (v.x - mean) * rstd; v.y = (v.y - mean) * rstd;
    v.z = (v.z - mean) * rstd; v.w = (v.w - mean) * rstd;
    op[i] = v;
  }
}

// ---------------------------------------------------------------------------
extern "C" void kernel_launch(void* const* d_in, const int* in_sizes, int n_in,
                              void* d_out, int out_size, void* d_ws, size_t ws_size,
                              hipStream_t stream) {
  const float* h_fea = (const float*)d_in[0];
  const float* aux   = (const float*)d_in[1];
  const float* Wq    = (const float*)d_in[2];
  const float* Wk    = (const float*)d_in[3];
  const float* Wv    = (const float*)d_in[4];
  const float* Wo    = (const float*)d_in[5];
  const float* W1    = (const float*)d_in[6];
  const float* b1    = (const float*)d_in[7];
  const float* W2    = (const float*)d_in[8];
  const float* b2    = (const float*)d_in[9];

  float* out = (float*)d_out;
  float* out_aux = out + (size_t)B_ * N_ * D_;          // output 1: aux passthrough

  float* ws = (float*)d_ws;
  const size_t QKV = (size_t)H_ * B_ * N_ * DH_;        // 2,097,152 floats
  float* Q     = ws;
  float* K     = ws + QKV;
  float* V     = ws + 2 * QKV;
  float* heads = ws + 3 * QKV;                          // [B,N,128]
  float* X     = ws + 4 * QKV;                          // [B,N,128]

  qkv_kernel<<<B_ * (N_ / 32), 256, 0, stream>>>(h_fea, Wq, Wk, Wv, Q, K, V);
  attn_kernel<<<B_ * (N_ / NT_), 256, 0, stream>>>(Q, K, V, aux, W1, b1, W2, b2,
                                                   heads, out_aux);
  wout_kernel<<<(B_ * N_) / 16, 256, 0, stream>>>(heads, Wo, h_fea, X);
  ln_kernel<<<B_, 1024, 0, stream>>>(X, out);
}

// Round 3
// 971.340 us; speedup vs baseline: 9.4944x; 9.4944x over previous
//
#include <hip/hip_runtime.h>
#include <hip/hip_bf16.h>

// Round 3 = round 2 resubmitted verbatim: round-2 bench died in container
// acquisition ("failed twice"), not in compile/correctness/timing.

// Shapes: H=8, D=128, DH=16, B=32, N=512
constexpr int H_ = 8;
constexpr int D_ = 128;
constexpr int DH_ = 16;
constexpr int B_ = 32;
constexpr int N_ = 512;

constexpr int NQ = 32;    // query rows per attn block
constexpr int MT = 16;    // m-tile (key rows per tile)
constexpr int KSTR = 260; // per-h float stride in Ks/Vs (260%32=4 -> banks 4h..4h+3)
constexpr int PSTR = 264; // per-m float stride in Ps (264%32=8 -> 2-way free)

__device__ __forceinline__ void load_lds16(const float* g, float* l) {
  __builtin_amdgcn_global_load_lds(
      (const __attribute__((address_space(1))) void*)g,
      (__attribute__((address_space(3))) void*)l, 16, 0, 0);
}

// ---------------------------------------------------------------------------
// Kernel 1: QKV projection.  grid = (b,h) = 256 blocks, 256 threads.
// Q/K/V layout: [H][B][N][DH].  Also zeroes the LN-stat accumulators.
// ---------------------------------------------------------------------------
__global__ __launch_bounds__(256) void qkv_kernel(
    const float* __restrict__ h_fea, const float* __restrict__ Wq,
    const float* __restrict__ Wk, const float* __restrict__ Wv,
    float* __restrict__ Q, float* __restrict__ K, float* __restrict__ V,
    float* __restrict__ stats)
{
  __shared__ float wqs[128 * 16], wks[128 * 16], wvs[128 * 16];
  __shared__ float hs[64 * 132];          // stride 132: f4-aligned, banks r*4+d

  const int t = threadIdx.x;
  const int h = blockIdx.x & 7;
  const int b = blockIdx.x >> 3;

  if (blockIdx.x == 0 && t < 64) stats[t] = 0.f;   // zero LN accumulators

  // stage weights once: 512 float4 each
#pragma unroll
  for (int i = 0; i < 2; ++i) {
    int idx4 = t + i * 256;
    ((float4*)wqs)[idx4] = ((const float4*)(Wq + (size_t)h * 2048))[idx4];
    ((float4*)wks)[idx4] = ((const float4*)(Wk + (size_t)h * 2048))[idx4];
    ((float4*)wvs)[idx4] = ((const float4*)(Wv + (size_t)h * 2048))[idx4];
  }

  const int r = t >> 2;                    // 64 rows
  const int e0 = (t & 3) * 4;              // 4 outputs each
  for (int chunk = 0; chunk < N_; chunk += 64) {
    __syncthreads();                       // hs safe from previous readers
#pragma unroll
    for (int i = 0; i < 8; ++i) {          // stage 64x128 h_fea chunk
      int idx4 = t + i * 256;
      int rr = idx4 >> 5, c4 = idx4 & 31;
      float4 v = ((const float4*)(h_fea + ((size_t)b * N_ + chunk + rr) * D_))[c4];
      *(float4*)&hs[rr * 132 + c4 * 4] = v;
    }
    __syncthreads();
    float aq0 = 0.f, aq1 = 0.f, aq2 = 0.f, aq3 = 0.f;
    float ak0 = 0.f, ak1 = 0.f, ak2 = 0.f, ak3 = 0.f;
    float av0 = 0.f, av1 = 0.f, av2 = 0.f, av3 = 0.f;
    for (int d = 0; d < D_; ++d) {
      float x = hs[r * 132 + d];
      float4 wq4 = *(const float4*)&wqs[d * 16 + e0];
      float4 wk4 = *(const float4*)&wks[d * 16 + e0];
      float4 wv4 = *(const float4*)&wvs[d * 16 + e0];
      aq0 = fmaf(x, wq4.x, aq0); aq1 = fmaf(x, wq4.y, aq1);
      aq2 = fmaf(x, wq4.z, aq2); aq3 = fmaf(x, wq4.w, aq3);
      ak0 = fmaf(x, wk4.x, ak0); ak1 = fmaf(x, wk4.y, ak1);
      ak2 = fmaf(x, wk4.z, ak2); ak3 = fmaf(x, wk4.w, ak3);
      av0 = fmaf(x, wv4.x, av0); av1 = fmaf(x, wv4.y, av1);
      av2 = fmaf(x, wv4.z, av2); av3 = fmaf(x, wv4.w, av3);
    }
    size_t o = ((size_t)(h * B_ + b) * N_ + chunk + r) * DH_ + e0;
    *(float4*)(Q + o) = make_float4(aq0, aq1, aq2, aq3);
    *(float4*)(K + o) = make_float4(ak0, ak1, ak2, ak3);
    *(float4*)(V + o) = make_float4(av0, av1, av2, av3);
  }
}

// ---------------------------------------------------------------------------
// Kernel 2: fused qk + aux passthrough + score MLP + no-max softmax + PV.
// grid = B*(N/NQ) = 512 blocks (XCD-swizzled), 256 threads (4 waves).
// ---------------------------------------------------------------------------
__global__ __launch_bounds__(256) void attn_kernel(
    const float* __restrict__ Q, const float* __restrict__ K, const float* __restrict__ V,
    const float* __restrict__ aux, const float* __restrict__ W1, const float* __restrict__ b1,
    const float* __restrict__ W2, const float* __restrict__ b2,
    float* __restrict__ heads, float* __restrict__ out_aux)
{
  __shared__ float Ks[2][8 * KSTR];
  __shared__ float Vs[2][8 * KSTR];
  __shared__ float Ps[MT * PSTR];
  __shared__ float Aux_s[8 * NQ * MT];     // [h][n][m], 16 KB
  __shared__ float W1s[256], W2s[128], b1s[16], b2s[8];

  const int t = threadIdx.x;
  // XCD swizzle: 512 blocks, 64-block contiguous chunk per XCD (4 b's each)
  const int lid = blockIdx.x;
  const int bx = (lid & 7) * 64 + (lid >> 3);
  const int b = bx >> 4;
  const int n0 = (bx & 15) * NQ;

  W1s[t & 255] = W1[t & 255];
  if (t < 128) W2s[t] = W2[t];
  if (t < 16) b1s[t] = b1[t];
  else if (t < 24) b2s[t - 16] = b2[t - 16];

  const int n = t >> 3;                    // 0..31
  const int h = t & 7;
  const int wv = t >> 6, lane = t & 63;

  // Q fragment held in registers for the whole kernel
  const float* qptr = Q + ((size_t)(h * B_ + b) * N_ + n0 + n) * DH_;
  const float4 q0 = ((const float4*)qptr)[0];
  const float4 q1 = ((const float4*)qptr)[1];
  const float4 q2 = ((const float4*)qptr)[2];
  const float4 q3 = ((const float4*)qptr)[3];

  float acc[16];
#pragma unroll
  for (int i = 0; i < 16; ++i) acc[i] = 0.f;
  float l = 0.f;

  // stage K/V tile 0
#pragma unroll
  for (int i = 0; i < 2; ++i) {
    int hh = i * 4 + wv;
    const float* gK = K + ((size_t)(hh * B_ + b) * N_ + 0) * DH_ + lane * 4;
    const float* gV = V + ((size_t)(hh * B_ + b) * N_ + 0) * DH_ + lane * 4;
    load_lds16(gK, &Ks[0][hh * KSTR]);
    load_lds16(gV, &Vs[0][hh * KSTR]);
  }

  for (int tile = 0; tile < N_ / MT; ++tile) {
    const int m0 = tile * MT;
    const int buf = tile & 1;
    __syncthreads();   // prev PV done with Ps/Vs/Aux_s; staged tile visible

    // stage aux tile for THIS tile (consumed after next barrier)
#pragma unroll
    for (int j = 0; j < 4; ++j) {
      int row = (wv * 4 + j) * 16 + (lane >> 2);      // row = h*32 + n
      int hh = row >> 5, nn = row & 31;
      const float* g = aux + ((size_t)(hh * B_ + b) * N_ + n0 + nn) * N_ + m0 + (lane & 3) * 4;
      load_lds16(g, &Aux_s[(wv * 4 + j) * 256]);
    }
    // stage K/V for NEXT tile
    if (tile + 1 < N_ / MT) {
#pragma unroll
      for (int i = 0; i < 2; ++i) {
        int hh = i * 4 + wv;
        const float* gK = K + ((size_t)(hh * B_ + b) * N_ + m0 + MT) * DH_ + lane * 4;
        const float* gV = V + ((size_t)(hh * B_ + b) * N_ + m0 + MT) * DH_ + lane * 4;
        load_lds16(gK, &Ks[buf ^ 1][hh * KSTR]);
        load_lds16(gV, &Vs[buf ^ 1][hh * KSTR]);
      }
    }

    // ---- qk phase: thread (n,h) computes MT dots ----
#pragma unroll 4
    for (int m = 0; m < MT; ++m) {
      const float4* kp = (const float4*)&Ks[buf][h * KSTR + m * 16];
      float4 k0 = kp[0], k1 = kp[1], k2 = kp[2], k3 = kp[3];
      float d = q0.x * k0.x + q0.y * k0.y + q0.z * k0.z + q0.w * k0.w
              + q1.x * k1.x + q1.y * k1.y + q1.z * k1.z + q1.w * k1.w
              + q2.x * k2.x + q2.y * k2.y + q2.z * k2.z + q2.w * k2.w
              + q3.x * k3.x + q3.y * k3.y + q3.z * k3.z + q3.w * k3.w;
      Ps[m * PSTR + n * 8 + h] = d;
    }
    __syncthreads();   // qk visible; aux staged (barrier drains vmcnt)

    // ---- MLP phase: 2 pairs per thread ----
#pragma unroll
    for (int i = 0; i < 2; ++i) {
      const int pn = (t >> 4) + 16 * i;
      const int pm = t & 15;
      float c[16];
      const float4* pr = (const float4*)&Ps[pm * PSTR + pn * 8];
      float4 ca = pr[0], cb = pr[1];
      c[0] = ca.x; c[1] = ca.y; c[2] = ca.z; c[3] = ca.w;
      c[4] = cb.x; c[5] = cb.y; c[6] = cb.z; c[7] = cb.w;
#pragma unroll
      for (int hh = 0; hh < 8; ++hh) c[8 + hh] = Aux_s[(hh * 32 + pn) * 16 + pm];
      float hid[16];
#pragma unroll
      for (int j = 0; j < 16; ++j) hid[j] = b1s[j];
#pragma unroll
      for (int ii = 0; ii < 16; ++ii) {
        float ci = c[ii];
#pragma unroll
        for (int j = 0; j < 16; ++j) hid[j] = fmaf(ci, W1s[ii * 16 + j], hid[j]);
      }
      float s8[8];
#pragma unroll
      for (int hh = 0; hh < 8; ++hh) s8[hh] = b2s[hh];
#pragma unroll
      for (int j = 0; j < 16; ++j) {
        float hj = fmaxf(hid[j], 0.f);
#pragma unroll
        for (int hh = 0; hh < 8; ++hh) s8[hh] = fmaf(hj, W2s[j * 8 + hh], s8[hh]);
      }
      float4 pa = make_float4(__expf(s8[0]), __expf(s8[1]), __expf(s8[2]), __expf(s8[3]));
      float4 pb = make_float4(__expf(s8[4]), __expf(s8[5]), __expf(s8[6]), __expf(s8[7]));
      float4* pw = (float4*)&Ps[pm * PSTR + pn * 8];
      pw[0] = pa; pw[1] = pb;
    }
    // ---- aux copy-out from LDS (one 64B row per thread) ----
    {
      const int hh = t >> 5, nn = t & 31;
      float* g = out_aux + ((size_t)(hh * B_ + b) * N_ + n0 + nn) * N_ + m0;
      const float4* s4 = (const float4*)&Aux_s[t * 16];
      float4* g4 = (float4*)g;
      g4[0] = s4[0]; g4[1] = s4[1]; g4[2] = s4[2]; g4[3] = s4[3];
    }
    __syncthreads();   // exp(P) visible

    // ---- PV phase: thread (n,h) accumulates ----
#pragma unroll 4
    for (int m = 0; m < MT; ++m) {
      float pm_ = Ps[m * PSTR + n * 8 + h];
      l += pm_;
      const float4* vp = (const float4*)&Vs[buf][h * KSTR + m * 16];
      float4 v0 = vp[0], v1 = vp[1], v2 = vp[2], v3 = vp[3];
      acc[0] = fmaf(pm_, v0.x, acc[0]);  acc[1] = fmaf(pm_, v0.y, acc[1]);
      acc[2] = fmaf(pm_, v0.z, acc[2]);  acc[3] = fmaf(pm_, v0.w, acc[3]);
      acc[4] = fmaf(pm_, v1.x, acc[4]);  acc[5] = fmaf(pm_, v1.y, acc[5]);
      acc[6] = fmaf(pm_, v1.z, acc[6]);  acc[7] = fmaf(pm_, v1.w, acc[7]);
      acc[8] = fmaf(pm_, v2.x, acc[8]);  acc[9] = fmaf(pm_, v2.y, acc[9]);
      acc[10] = fmaf(pm_, v2.z, acc[10]); acc[11] = fmaf(pm_, v2.w, acc[11]);
      acc[12] = fmaf(pm_, v3.x, acc[12]); acc[13] = fmaf(pm_, v3.y, acc[13]);
      acc[14] = fmaf(pm_, v3.z, acc[14]); acc[15] = fmaf(pm_, v3.w, acc[15]);
    }
  }

  const float inv = 1.0f / l;
  float* hp = heads + ((size_t)b * N_ + n0 + n) * D_ + h * DH_;
  ((float4*)hp)[0] = make_float4(acc[0] * inv, acc[1] * inv, acc[2] * inv, acc[3] * inv);
  ((float4*)hp)[1] = make_float4(acc[4] * inv, acc[5] * inv, acc[6] * inv, acc[7] * inv);
  ((float4*)hp)[2] = make_float4(acc[8] * inv, acc[9] * inv, acc[10] * inv, acc[11] * inv);
  ((float4*)hp)[3] = make_float4(acc[12] * inv, acc[13] * inv, acc[14] * inv, acc[15] * inv);
}

// ---------------------------------------------------------------------------
// Kernel 3: X = heads @ W_out + h_fea, plus LN partial sums via atomics.
// 16 rows per block, 256 threads.
// ---------------------------------------------------------------------------
__global__ __launch_bounds__(256) void wout_kernel(
    const float* __restrict__ heads, const float* __restrict__ Wo,
    const float* __restrict__ h_fea, float* __restrict__ X,
    float* __restrict__ stats)
{
  __shared__ float wos[128 * 128];
  __shared__ float hsd[16][129];
  __shared__ float rs[4], rq[4];
  const int t = threadIdx.x;
  const int r0 = blockIdx.x * 16;
  const int b = r0 >> 9;
#pragma unroll
  for (int i = 0; i < 16; ++i) {
    int idx4 = t + i * 256;
    ((float4*)wos)[idx4] = ((const float4*)Wo)[idx4];
  }
#pragma unroll
  for (int i = 0; i < 2; ++i) {
    int idx4 = t + i * 256;
    int r = idx4 >> 5, c = (idx4 & 31) * 4;
    float4 v = ((const float4*)(heads + (size_t)(r0 + r) * D_))[idx4 & 31];
    hsd[r][c] = v.x; hsd[r][c + 1] = v.y; hsd[r][c + 2] = v.z; hsd[r][c + 3] = v.w;
  }
  __syncthreads();
  const int r = t >> 4, dg = t & 15;
  float acc[8];
#pragma unroll
  for (int i = 0; i < 8; ++i) acc[i] = 0.f;
  for (int k = 0; k < 128; ++k) {
    float hv = hsd[r][k];
#pragma unroll
    for (int i = 0; i < 8; ++i) acc[i] = fmaf(hv, wos[k * 128 + dg + 16 * i], acc[i]);
  }
  size_t base = (size_t)(r0 + r) * D_;
  float s = 0.f, sq = 0.f;
#pragma unroll
  for (int i = 0; i < 8; ++i) {
    int d = dg + 16 * i;
    float v = acc[i] + h_fea[base + d];
    X[base + d] = v;
    s += v; sq += v * v;
  }
#pragma unroll
  for (int o = 32; o; o >>= 1) { s += __shfl_down(s, o); sq += __shfl_down(sq, o); }
  const int wv = t >> 6, lane = t & 63;
  if (lane == 0) { rs[wv] = s; rq[wv] = sq; }
  __syncthreads();
  if (t == 0) {
    s = rs[0] + rs[1] + rs[2] + rs[3];
    sq = rq[0] + rq[1] + rq[2] + rq[3];
    atomicAdd(&stats[b * 2], s);
    atomicAdd(&stats[b * 2 + 1], sq);
  }
}

// ---------------------------------------------------------------------------
// Kernel 4: normalize.  grid = B*8 = 256 blocks, 256 threads.
// ---------------------------------------------------------------------------
__global__ __launch_bounds__(256) void ln_kernel(
    const float* __restrict__ X, const float* __restrict__ stats,
    float* __restrict__ out)
{
  const int b = blockIdx.x >> 3;
  const int sl = blockIdx.x & 7;
  const float M = (float)(N_ * D_);
  const float ts = stats[b * 2], tq = stats[b * 2 + 1];
  const float mean = ts / M;
  const float rstd = rsqrtf((tq - ts * ts / M) / (M - 1.0f) + 1e-5f);
  const size_t base4 = ((size_t)b * (N_ * D_) + sl * 8192) / 4;
  const float4* xp = (const float4*)X + base4;
  float4* op = (float4*)out + base4;
  const int t = threadIdx.x;
#pragma unroll
  for (int i = 0; i < 8; ++i) {
    float4 v = xp[t + i * 256];
    v.x = (v.x - mean) * rstd; v.y = (v.y - mean) * rstd;
    v.z = (v.z - mean) * rstd; v.w = (v.w - mean) * rstd;
    op[t + i * 256] = v;
  }
}

// ---------------------------------------------------------------------------
extern "C" void kernel_launch(void* const* d_in, const int* in_sizes, int n_in,
                              void* d_out, int out_size, void* d_ws, size_t ws_size,
                              hipStream_t stream) {
  const float* h_fea = (const float*)d_in[0];
  const float* aux   = (const float*)d_in[1];
  const float* Wq    = (const float*)d_in[2];
  const float* Wk    = (const float*)d_in[3];
  const float* Wv    = (const float*)d_in[4];
  const float* Wo    = (const float*)d_in[5];
  const float* W1    = (const float*)d_in[6];
  const float* b1    = (const float*)d_in[7];
  const float* W2    = (const float*)d_in[8];
  const float* b2    = (const float*)d_in[9];

  float* out = (float*)d_out;
  float* out_aux = out + (size_t)B_ * N_ * D_;          // output 1: aux passthrough

  float* ws = (float*)d_ws;
  const size_t SEG = (size_t)H_ * B_ * N_ * DH_;        // 2,097,152 floats
  float* Q     = ws;
  float* K     = ws + SEG;
  float* V     = ws + 2 * SEG;
  float* heads = ws + 3 * SEG;                          // [B,N,128]
  float* X     = ws + 4 * SEG;                          // [B,N,128]
  float* stats = ws + 5 * SEG;                          // 64 floats

  qkv_kernel<<<B_ * H_, 256, 0, stream>>>(h_fea, Wq, Wk, Wv, Q, K, V, stats);
  attn_kernel<<<B_ * (N_ / NQ), 256, 0, stream>>>(Q, K, V, aux, W1, b1, W2, b2,
                                                  heads, out_aux);
  wout_kernel<<<(B_ * N_) / 16, 256, 0, stream>>>(heads, Wo, h_fea, X, stats);
  ln_kernel<<<B_ * 8, 256, 0, stream>>>(X, stats, out);
}